// Round 2
// 556.328 us; speedup vs baseline: 1.0238x; 1.0238x over previous
//
#include <hip/hip_runtime.h>
#include <hip/hip_bf16.h>

// Superpoint MAE: fused MLP (32->64->128, relu) + segment_max(50K), MI355X.
//
// R5 post-mortem: main kernel 220us is VALU-bound (MfmaUtil 7%, VALUBusy 48%,
// HBM 7%): manual f2bf (3 VALU/value, 24/tile on X + 48/tile on h1 staging),
// the h1 LDS transpose round trip (16 ds_write + 2 ds_read + TWO lgkmcnt(0)
// full stalls per tile at only ~2.3 waves/SIMD), and 925K LDS bank conflicts
// in that staging. build_slots is a serial idx->atomic->store latency chain.
//
// R6 (this version; R6 submission hit an infra "container failed twice" —
// resubmitted unchanged):
//  - Swapped-operand layer 1: mfma(w1f, x) computes h^T, so each lane's C
//    fragment holds 16 h-values of ITS OWN point (col=l16=point,
//    row = t*16 + quad*4 + r). With the K-axis of layer 2 permuted by
//    sigma(quad,j) = (j>>2)*16 + quad*4 + (j&3) -- applied identically to the
//    W2 fragments at setup (free) -- layer-1 output feeds layer-2 MFMAs
//    directly in registers. LDS transpose, its two per-tile lgkmcnt(0)
//    stalls, and its bank conflicts are gone.
//  - All hot f32->bf16 via v_cvt_pk_bf16_f32 (1 instr / 2 values).
//  - Layer-2 epilogue: add + fusable max3(vmax, x, 0).
//  - build_slots: 3-way unrolled (loads, then independent atomics, then
//    stores) so atomic round trips overlap; block 0 publishes the dtype flag
//    so both seg_mlp_max templates skip the 4KB probe (dead one exits on a
//    single word).

#define NPTS 1500000
#define NSEG 50000
#define CAP  120          // slots per segment; expected max count ~56

typedef __attribute__((ext_vector_type(8))) short short8;
typedef __attribute__((ext_vector_type(4))) float floatx4;
typedef __attribute__((ext_vector_type(2))) float floatx2;

__device__ __forceinline__ unsigned short f2bf(float f) {
    unsigned int x = __float_as_uint(f);
    x += 0x7FFFu + ((x >> 16) & 1u);   // RNE; finite inputs only
    return (unsigned short)(x >> 16);
}
__device__ __forceinline__ float bf2f(unsigned short b) {
    return __uint_as_float(((unsigned int)b) << 16);
}
// packed RNE convert: low16 = bf16(lo), high16 = bf16(hi)
__device__ __forceinline__ unsigned cvt_pk_bf16(float lo, float hi) {
    unsigned r;
    asm("v_cvt_pk_bf16_f32 %0, %1, %2" : "=v"(r) : "v"(lo), "v"(hi));
    return r;
}

__device__ __forceinline__ short8 load_x(const void* Xv, int pid, int quad, int isbf)
{
    if (isbf) {
        return *(const short8*)((const unsigned short*)Xv + (size_t)pid * 32 + quad * 8);
    } else {
        const float* xf = (const float*)Xv + (size_t)pid * 32 + quad * 8;
        const floatx4 f0 = *(const floatx4*)xf;
        const floatx4 f1 = *(const floatx4*)(xf + 4);
        union { short8 s; unsigned u[4]; } a;
        a.u[0] = cvt_pk_bf16(f0[0], f0[1]);
        a.u[1] = cvt_pk_bf16(f0[2], f0[3]);
        a.u[2] = cvt_pk_bf16(f1[0], f1[1]);
        a.u[3] = cvt_pk_bf16(f1[2], f1[3]);
        return a.s;
    }
}

// per-block probe: is idx int64?  (int64 -> odd 32b words all zero)
__device__ __forceinline__ int probe_idx64(const unsigned* idxw, unsigned* scnt)
{
    if (threadIdx.x == 0) *scnt = 0u;
    __syncthreads();
    int nz = 0;
    #pragma unroll
    for (int j = 0; j < 2; ++j)
        nz += (idxw[(threadIdx.x * 2 + j) * 2 + 1] != 0u) ? 1 : 0;
    atomicAdd(scnt, (unsigned)nz);
    __syncthreads();
    return (*scnt < 256u) ? 1 : 0;
}

// per-block probe: is X bf16?  (both 16b halves have sane exponents)
__device__ __forceinline__ int probe_isbf(const unsigned* Xw, unsigned* scnt)
{
    if (threadIdx.x == 0) *scnt = 0u;
    __syncthreads();
    int c = 0;
    #pragma unroll
    for (int j = 0; j < 4; ++j) {
        unsigned u  = Xw[threadIdx.x * 4 + j];
        unsigned he = (u >> 23) & 0xFFu, le = (u >> 7) & 0xFFu;
        c += (he >= 100u && he <= 140u && le >= 100u && le <= 140u) ? 1 : 0;
    }
    atomicAdd(scnt, (unsigned)c);
    __syncthreads();
    return (*scnt >= 512u) ? 1 : 0;
}

// ---------------- single-pass capacity-slotted bucketing ----------------
// 3-way unrolled so the three independent atomicAdd round trips overlap
// instead of forming one serial load->atomic->store chain per iteration.
// grid is fixed at 2048x256: 3 * 524288 = 1572864 >= NPTS covers all points.
__global__ __launch_bounds__(256)
void build_slots(const unsigned* __restrict__ idxw,
                 const unsigned* __restrict__ Xw,
                 unsigned* __restrict__ cnt,
                 int* __restrict__ slots,
                 unsigned* __restrict__ flags)
{
    __shared__ unsigned sc;
    const int idx64 = probe_idx64(idxw, &sc);

    if (blockIdx.x == 0) {            // publish dtype flag for the MLP kernels
        __syncthreads();
        const int isbf = probe_isbf(Xw, &sc);
        if (threadIdx.x == 0) flags[0] = (unsigned)isbf;
    }

    const int S  = gridDim.x * 256;
    const int i0 = blockIdx.x * 256 + threadIdx.x;
    const int i1 = i0 + S, i2 = i1 + S;

    unsigned s0 = 0xFFFFFFFFu, s1 = 0xFFFFFFFFu, s2 = 0xFFFFFFFFu;
    if (i0 < NPTS) s0 = idx64 ? idxw[2 * (size_t)i0] : idxw[i0];
    if (i1 < NPTS) s1 = idx64 ? idxw[2 * (size_t)i1] : idxw[i1];
    if (i2 < NPTS) s2 = idx64 ? idxw[2 * (size_t)i2] : idxw[i2];

    unsigned p0 = 0, p1 = 0, p2 = 0;
    if (s0 < NSEG) p0 = atomicAdd(&cnt[s0], 1u);
    if (s1 < NSEG) p1 = atomicAdd(&cnt[s1], 1u);
    if (s2 < NSEG) p2 = atomicAdd(&cnt[s2], 1u);

    if (s0 < NSEG && p0 < CAP) slots[(size_t)s0 * CAP + p0] = i0;
    if (s1 < NSEG && p1 < CAP) slots[(size_t)s1 * CAP + p1] = i1;
    if (s2 < NSEG && p2 < CAP) slots[(size_t)s2 * CAP + p2] = i2;
}

// ---------------- segment-centric fused MLP + register max ----------------
// DT: 1 = bf16 inputs/out, 0 = fp32 inputs/out. One wave per segment.
template<int DT>
__global__ __launch_bounds__(256)
void seg_mlp_max(const void* __restrict__ Xv,
                 const void* __restrict__ W1v, const void* __restrict__ B1v,
                 const void* __restrict__ W2v, const void* __restrict__ B2v,
                 const unsigned* __restrict__ cnt,
                 const int* __restrict__ slots,
                 const unsigned* __restrict__ flags,
                 void* __restrict__ outv)
{
    if (flags[0] != (unsigned)DT) return;   // dead template: 1 word, exit

    __shared__ __align__(16) float outs[4][128];   // per-wave output staging

    const int tid = threadIdx.x, wave = tid >> 6, lane = tid & 63;
    const int quad = lane >> 4, l16 = lane & 15;

    // W1 fragments, used as the A operand of the SWAPPED layer-1 mfma:
    // A[m = t*16+l16][k = quad*8+j] = W1[k][t*16+l16]
    short8 w1f[4];
    #pragma unroll
    for (int t = 0; t < 4; ++t)
        #pragma unroll
        for (int j = 0; j < 8; ++j) {
            const int e = (quad * 8 + j) * 64 + t * 16 + l16;
            w1f[t][j] = DT ? (short)((const unsigned short*)W1v)[e]
                           : (short)f2bf(((const float*)W1v)[e]);
        }

    // W2 fragments with the K-axis PERMUTED by sigma(quad,j):
    //   k_logical = kt*32 + (j>>2)*16 + quad*4 + (j&3)
    // This matches the layout in which layer-1's C fragment naturally lands,
    // so h feeds layer 2 directly from registers (mfma is K-permutation
    // invariant when A and B use the same permutation).
    short8 w2f[2][8];
    #pragma unroll
    for (int kt = 0; kt < 2; ++kt)
        #pragma unroll
        for (int t = 0; t < 8; ++t)
            #pragma unroll
            for (int j = 0; j < 8; ++j) {
                const int k = kt * 32 + (j >> 2) * 16 + quad * 4 + (j & 3);
                const int e = k * 128 + t * 16 + l16;
                w2f[kt][t][j] = DT ? (short)((const unsigned short*)W2v)[e]
                                   : (short)f2bf(((const float*)W2v)[e]);
            }

    // b1 per lane: hidden index n = t*16 + quad*4 + r  -> b1v[t*4+r]
    float b1v[16];
    #pragma unroll
    for (int t = 0; t < 4; ++t)
        #pragma unroll
        for (int r = 0; r < 4; ++r) {
            const int n = t * 16 + quad * 4 + r;
            b1v[t * 4 + r] = DT ? bf2f(((const unsigned short*)B1v)[n])
                                : ((const float*)B1v)[n];
        }
    float b2v[8];
    #pragma unroll
    for (int t = 0; t < 8; ++t)
        b2v[t] = DT ? bf2f(((const unsigned short*)B2v)[t * 16 + l16])
                    : ((const float*)B2v)[t * 16 + l16];

    float* fs = outs[wave];
    const int gw = blockIdx.x * 4 + wave, nw = gridDim.x * 4;

    for (int seg = gw; seg < NSEG; seg += nw) {
        const int c = min((int)cnt[seg], CAP);

        float vmax[8];
        #pragma unroll
        for (int t = 0; t < 8; ++t) vmax[t] = 0.f;

        if (c > 0) {
            const int nt = (c + 15) >> 4, last = c - 1;
            const size_t base = (size_t)seg * CAP;

            // issue BOTH leading tiles' gathers up-front (avg nt == 2);
            // tail lanes duplicate the last point: max-neutral
            short8 abuf[2];
            abuf[0] = load_x(Xv, slots[base + min(l16, last)], quad, DT);
            if (nt > 1)
                abuf[1] = load_x(Xv, slots[base + min(16 + l16, last)], quad, DT);

            for (int ti = 0; ti < nt; ++ti) {
                const short8 acur = abuf[ti & 1];
                if (ti + 2 < nt)   // rolling prefetch into the freed buffer
                    abuf[ti & 1] = load_x(
                        Xv, slots[base + min((ti + 2) * 16 + l16, last)], quad, DT);

                // layer 1 SWAPPED: C = W1^T * X^T.  Lane holds, for its own
                // point (col=l16), h_pre[n = t*16 + quad*4 + r].
                floatx4 c1[4];
                #pragma unroll
                for (int t = 0; t < 4; ++t) {
                    floatx4 z = {0.f, 0.f, 0.f, 0.f};
                    c1[t] = __builtin_amdgcn_mfma_f32_16x16x32_bf16(w1f[t], acur, z, 0, 0, 0);
                }

                // bias + relu + pack straight into layer-2 A fragments:
                // af[kt][j] = h[ t = kt*2 + (j>>2) ][ r = j&3 ]
                union { short8 s; unsigned u[4]; } af0, af1;
                #pragma unroll
                for (int t = 0; t < 4; ++t) {
                    const float h0 = fmaxf(c1[t][0] + b1v[t * 4 + 0], 0.f);
                    const float h1 = fmaxf(c1[t][1] + b1v[t * 4 + 1], 0.f);
                    const float h2 = fmaxf(c1[t][2] + b1v[t * 4 + 2], 0.f);
                    const float h3 = fmaxf(c1[t][3] + b1v[t * 4 + 3], 0.f);
                    const unsigned lo = cvt_pk_bf16(h0, h1);
                    const unsigned hi = cvt_pk_bf16(h2, h3);
                    if (t == 0)      { af0.u[0] = lo; af0.u[1] = hi; }
                    else if (t == 1) { af0.u[2] = lo; af0.u[3] = hi; }
                    else if (t == 2) { af1.u[0] = lo; af1.u[1] = hi; }
                    else             { af1.u[2] = lo; af1.u[3] = hi; }
                }

                // layer 2 + in-register max (K permuted identically via w2f)
                #pragma unroll
                for (int t = 0; t < 8; ++t) {
                    floatx4 c4 = {0.f, 0.f, 0.f, 0.f};
                    c4 = __builtin_amdgcn_mfma_f32_16x16x32_bf16(af0.s, w2f[0][t], c4, 0, 0, 0);
                    c4 = __builtin_amdgcn_mfma_f32_16x16x32_bf16(af1.s, w2f[1][t], c4, 0, 0, 0);
                    #pragma unroll
                    for (int r = 0; r < 4; ++r)   // max3(vmax, x+b, 0)
                        vmax[t] = fmaxf(fmaxf(vmax[t], c4[r] + b2v[t]), 0.f);
                }
            }
        }

        // cross-quad reduce; 256B coalesced row store via LDS staging
        #pragma unroll
        for (int t = 0; t < 8; ++t) {
            vmax[t] = fmaxf(vmax[t], __shfl_xor(vmax[t], 16, 64));
            vmax[t] = fmaxf(vmax[t], __shfl_xor(vmax[t], 32, 64));
        }
        if (quad == 0) {
            #pragma unroll
            for (int t = 0; t < 8; ++t) fs[t * 16 + l16] = vmax[t];
        }
        __builtin_amdgcn_s_waitcnt(0xC07F);   // lgkmcnt(0): LDS w->r (same wave)
        const floatx2 o2 = ((const floatx2*)fs)[lane];
        if (DT) {
            ((unsigned*)outv)[seg * 64 + lane] = cvt_pk_bf16(o2[0], o2[1]);
        } else {
            ((floatx2*)outv)[seg * 64 + lane] = o2;
        }
        __builtin_amdgcn_s_waitcnt(0xC07F);   // fs reads before next seg's writes
    }
}

// ==================== host launch ====================
extern "C" void kernel_launch(void* const* d_in, const int* in_sizes, int n_in,
                              void* d_out, int out_size, void* d_ws, size_t ws_size,
                              hipStream_t stream)
{
    const void* X   = d_in[0];
    const void* idx = d_in[1];
    const void* W1  = d_in[2];
    const void* B1  = d_in[3];
    const void* W2  = d_in[4];
    const void* B2  = d_in[5];

    // ws layout: cnt 200,000 B | flags 64 B | slots 24 MB
    char* w = (char*)d_ws;
    unsigned* cnt   = (unsigned*)w;  w += ((size_t)NSEG * 4 + 63) & ~63ull;
    unsigned* flags = (unsigned*)w;  w += 64;
    int*      slots = (int*)w;

    hipMemsetAsync(cnt, 0, (size_t)NSEG * 4, stream);
    build_slots<<<2048, 256, 0, stream>>>((const unsigned*)idx, (const unsigned*)X,
                                          cnt, slots, flags);
    seg_mlp_max<1><<<4096, 256, 0, stream>>>(X, W1, B1, W2, B2, cnt, slots, flags, d_out);
    seg_mlp_max<0><<<4096, 256, 0, stream>>>(X, W1, B1, W2, B2, cnt, slots, flags, d_out);
}

// Round 4
// 449.331 us; speedup vs baseline: 1.2676x; 1.2381x over previous
//
#include <hip/hip_runtime.h>
#include <hip/hip_bf16.h>

// Superpoint MAE: fused MLP (32->64->128, relu) + segment_max(50K), MI355X.
//
// R6 post-mortem: removing the LDS transpose removed VALU (48->37%) and bank
// conflicts (925K->0) but the kernel got SLOWER (220->242us): the real wall
// is the per-segment serial chain of dependent random loads (cnt -> slots ->
// X row gather, ~3 x 600-900cy) at ~6 waves/CU. 528 GB/s = latency exposure.
//
// R7 (crashed): moved the random access to the WRITE side (scatter bf16 rows
// into capacity-slotted Xs; main kernel reads contiguous tiles). The crash
// was a shared-counter race: build_rows ran probe_idx64 and probe_isbf
// back-to-back in every block with no barrier between the last read of sc
// and the next probe's zero-write -> waves 1-3 could see sc==0 -> misdetect
// idx64/isbf -> OOB reads (12MB into 6MB idx buffer) -> GPU fault.
//
// R8: probes are now internally safe (LEADING __syncthreads() before the
// zero-write: every thread's read of the previous probe's result precedes
// the barrier, so read-before-overwrite is guaranteed). No other changes.

#define NPTS 1500000
#define NSEG 50000
#define CAP  120          // index slots per segment (overflow-safe path)
#define CAPX 64           // row slots per segment; expected max count ~56

typedef __attribute__((ext_vector_type(8))) short short8;
typedef __attribute__((ext_vector_type(4))) float floatx4;
typedef __attribute__((ext_vector_type(2))) float floatx2;
typedef __attribute__((ext_vector_type(4))) unsigned int uintx4;

__device__ __forceinline__ unsigned short f2bf(float f) {
    unsigned int x = __float_as_uint(f);
    x += 0x7FFFu + ((x >> 16) & 1u);   // RNE; finite inputs only
    return (unsigned short)(x >> 16);
}
__device__ __forceinline__ float bf2f(unsigned short b) {
    return __uint_as_float(((unsigned int)b) << 16);
}
// packed RNE convert: low16 = bf16(lo), high16 = bf16(hi)
__device__ __forceinline__ unsigned cvt_pk_bf16(float lo, float hi) {
    unsigned r;
    asm("v_cvt_pk_bf16_f32 %0, %1, %2" : "=v"(r) : "v"(lo), "v"(hi));
    return r;
}

__device__ __forceinline__ short8 load_x(const void* Xv, int pid, int quad, int isbf)
{
    if (isbf) {
        return *(const short8*)((const unsigned short*)Xv + (size_t)pid * 32 + quad * 8);
    } else {
        const float* xf = (const float*)Xv + (size_t)pid * 32 + quad * 8;
        const floatx4 f0 = *(const floatx4*)xf;
        const floatx4 f1 = *(const floatx4*)(xf + 4);
        union { short8 s; unsigned u[4]; } a;
        a.u[0] = cvt_pk_bf16(f0[0], f0[1]);
        a.u[1] = cvt_pk_bf16(f0[2], f0[3]);
        a.u[2] = cvt_pk_bf16(f1[0], f1[1]);
        a.u[3] = cvt_pk_bf16(f1[2], f1[3]);
        return a.s;
    }
}

// per-block probe: is idx int64?  (int64 -> odd 32b words all zero)
// LEADING barrier protects any prior reader of *scnt (safe to chain probes).
__device__ __forceinline__ int probe_idx64(const unsigned* idxw, unsigned* scnt)
{
    __syncthreads();
    if (threadIdx.x == 0) *scnt = 0u;
    __syncthreads();
    int nz = 0;
    #pragma unroll
    for (int j = 0; j < 2; ++j)
        nz += (idxw[(threadIdx.x * 2 + j) * 2 + 1] != 0u) ? 1 : 0;
    atomicAdd(scnt, (unsigned)nz);
    __syncthreads();
    return (*scnt < 256u) ? 1 : 0;
}

// per-block probe: is X bf16?  (both 16b halves have sane exponents)
__device__ __forceinline__ int probe_isbf(const unsigned* Xw, unsigned* scnt)
{
    __syncthreads();
    if (threadIdx.x == 0) *scnt = 0u;
    __syncthreads();
    int c = 0;
    #pragma unroll
    for (int j = 0; j < 4; ++j) {
        unsigned u  = Xw[threadIdx.x * 4 + j];
        unsigned he = (u >> 23) & 0xFFu, le = (u >> 7) & 0xFFu;
        c += (he >= 100u && he <= 140u && le >= 100u && le <= 140u) ? 1 : 0;
    }
    atomicAdd(scnt, (unsigned)c);
    __syncthreads();
    return (*scnt >= 512u) ? 1 : 0;
}

// read one point row, convert to bf16 (4 x 16B words)
__device__ __forceinline__ void load_row(const unsigned* Xw, int i, int isbf, uintx4 r[4])
{
    if (isbf) {
        const uintx4* s = (const uintx4*)((const char*)Xw + (size_t)i * 64);
        r[0] = s[0]; r[1] = s[1]; r[2] = s[2]; r[3] = s[3];
    } else {
        const floatx4* f = (const floatx4*)((const char*)Xw + (size_t)i * 128);
        #pragma unroll
        for (int k = 0; k < 4; ++k) {
            const floatx4 a = f[2 * k], b = f[2 * k + 1];
            uintx4 w;
            w[0] = cvt_pk_bf16(a[0], a[1]);
            w[1] = cvt_pk_bf16(a[2], a[3]);
            w[2] = cvt_pk_bf16(b[0], b[1]);
            w[3] = cvt_pk_bf16(b[2], b[3]);
            r[k] = w;
        }
    }
}

// ============ R7 fast path: build (stream read X, scatter bf16 rows) ============
// grid 3072x256, 2 points/thread: 1,572,864 >= NPTS.
__global__ __launch_bounds__(256)
void build_rows(const unsigned* __restrict__ idxw,
                const unsigned* __restrict__ Xw,
                unsigned* __restrict__ cnt,
                int* __restrict__ slots,
                unsigned short* __restrict__ Xs,
                unsigned* __restrict__ flags)
{
    __shared__ unsigned sc;
    const int idx64 = probe_idx64(idxw, &sc);
    const int isbf  = probe_isbf(Xw, &sc);   // safe: probe has leading barrier
    if (blockIdx.x == 0 && threadIdx.x == 0) flags[0] = (unsigned)isbf;

    const int S  = gridDim.x * 256;
    const int i0 = blockIdx.x * 256 + threadIdx.x;
    const int i1 = i0 + S;

    unsigned s0 = 0xFFFFFFFFu, s1 = 0xFFFFFFFFu;
    if (i0 < NPTS) s0 = idx64 ? idxw[2 * (size_t)i0] : idxw[i0];
    if (i1 < NPTS) s1 = idx64 ? idxw[2 * (size_t)i1] : idxw[i1];

    // rows load+convert first (independent of the atomic round trips)
    uintx4 r0[4], r1[4];
    if (s0 < NSEG) load_row(Xw, i0, isbf, r0);
    if (s1 < NSEG) load_row(Xw, i1, isbf, r1);

    unsigned p0 = 0, p1 = 0;
    if (s0 < NSEG) p0 = atomicAdd(&cnt[s0], 1u);
    if (s1 < NSEG) p1 = atomicAdd(&cnt[s1], 1u);

    if (s0 < NSEG) {
        if (p0 < CAP)  slots[(size_t)s0 * CAP + p0] = i0;
        if (p0 < CAPX) {
            uintx4* d = (uintx4*)(Xs + ((size_t)s0 * CAPX + p0) * 32);
            d[0] = r0[0]; d[1] = r0[1]; d[2] = r0[2]; d[3] = r0[3];
        }
    }
    if (s1 < NSEG) {
        if (p1 < CAP)  slots[(size_t)s1 * CAP + p1] = i1;
        if (p1 < CAPX) {
            uintx4* d = (uintx4*)(Xs + ((size_t)s1 * CAPX + p1) * 32);
            d[0] = r1[0]; d[1] = r1[1]; d[2] = r1[2]; d[3] = r1[3];
        }
    }
}

// one 16-point tile through the MLP, updating vmax[8]; lanes whose point
// p = quad*4+r is >= lim contribute 0 (masked) unless full.
__device__ __forceinline__ void tile_mlp(const short8 acur,
                                         const short8 w1f[4],
                                         const short8 w2f[2][8],
                                         const float b1v[16],
                                         const float b2v[8],
                                         float vmax[8],
                                         const int quad,
                                         const int lim, const bool full)
{
    // layer 1 SWAPPED: C = W1^T * X^T; lane holds h[n = t*16+quad*4+r] of
    // its own point (col = l16).
    floatx4 c1[4];
    #pragma unroll
    for (int t = 0; t < 4; ++t) {
        floatx4 z = {0.f, 0.f, 0.f, 0.f};
        c1[t] = __builtin_amdgcn_mfma_f32_16x16x32_bf16(w1f[t], acur, z, 0, 0, 0);
    }

    // bias + relu + pack straight into layer-2 A fragments
    union { short8 s; unsigned u[4]; } af0, af1;
    #pragma unroll
    for (int t = 0; t < 4; ++t) {
        const float h0 = fmaxf(c1[t][0] + b1v[t * 4 + 0], 0.f);
        const float h1 = fmaxf(c1[t][1] + b1v[t * 4 + 1], 0.f);
        const float h2 = fmaxf(c1[t][2] + b1v[t * 4 + 2], 0.f);
        const float h3 = fmaxf(c1[t][3] + b1v[t * 4 + 3], 0.f);
        const unsigned lo = cvt_pk_bf16(h0, h1);
        const unsigned hi = cvt_pk_bf16(h2, h3);
        if (t == 0)      { af0.u[0] = lo; af0.u[1] = hi; }
        else if (t == 1) { af0.u[2] = lo; af0.u[3] = hi; }
        else if (t == 2) { af1.u[0] = lo; af1.u[1] = hi; }
        else             { af1.u[2] = lo; af1.u[3] = hi; }
    }

    // layer 2 + in-register max (K permuted identically via w2f);
    // C row = point p = quad*4+r, col = embed l16.
    #pragma unroll
    for (int t = 0; t < 8; ++t) {
        floatx4 c4 = {0.f, 0.f, 0.f, 0.f};
        c4 = __builtin_amdgcn_mfma_f32_16x16x32_bf16(af0.s, w2f[0][t], c4, 0, 0, 0);
        c4 = __builtin_amdgcn_mfma_f32_16x16x32_bf16(af1.s, w2f[1][t], c4, 0, 0, 0);
        #pragma unroll
        for (int r = 0; r < 4; ++r) {
            const float v = c4[r] + b2v[t];
            vmax[t] = fmaxf(vmax[t], (full || (quad * 4 + r) < lim) ? v : 0.f);
        }
    }
}

__device__ __forceinline__ short8 row_tile(const unsigned short* Xs, int seg,
                                           int ti, int l16, int quad)
{
    return *(const short8*)(Xs + ((size_t)seg * CAPX + ti * 16 + l16) * 32 + quad * 8);
}

// ============ R7 fast path: main (contiguous Xs tiles, seg pipelining) ============
template<int DT>
__global__ __launch_bounds__(256)
void seg_mlp_rows(const void* __restrict__ Xv,
                  const void* __restrict__ W1v, const void* __restrict__ B1v,
                  const void* __restrict__ W2v, const void* __restrict__ B2v,
                  const unsigned* __restrict__ cnt,
                  const int* __restrict__ slots,
                  const unsigned short* __restrict__ Xs,
                  const unsigned* __restrict__ flags,
                  void* __restrict__ outv)
{
    if (flags[0] != (unsigned)DT) return;   // dead template: 1 word, exit

    __shared__ __align__(16) float outs[4][128];   // per-wave output staging

    const int tid = threadIdx.x, wave = tid >> 6, lane = tid & 63;
    const int quad = lane >> 4, l16 = lane & 15;

    // W1 fragments (A operand of the swapped layer-1 mfma)
    short8 w1f[4];
    #pragma unroll
    for (int t = 0; t < 4; ++t)
        #pragma unroll
        for (int j = 0; j < 8; ++j) {
            const int e = (quad * 8 + j) * 64 + t * 16 + l16;
            w1f[t][j] = DT ? (short)((const unsigned short*)W1v)[e]
                           : (short)f2bf(((const float*)W1v)[e]);
        }

    // W2 fragments, K-axis permuted by sigma(quad,j) = (j>>2)*16+quad*4+(j&3)
    short8 w2f[2][8];
    #pragma unroll
    for (int kt = 0; kt < 2; ++kt)
        #pragma unroll
        for (int t = 0; t < 8; ++t)
            #pragma unroll
            for (int j = 0; j < 8; ++j) {
                const int k = kt * 32 + (j >> 2) * 16 + quad * 4 + (j & 3);
                const int e = k * 128 + t * 16 + l16;
                w2f[kt][t][j] = DT ? (short)((const unsigned short*)W2v)[e]
                                   : (short)f2bf(((const float*)W2v)[e]);
            }

    float b1v[16];
    #pragma unroll
    for (int t = 0; t < 4; ++t)
        #pragma unroll
        for (int r = 0; r < 4; ++r) {
            const int n = t * 16 + quad * 4 + r;
            b1v[t * 4 + r] = DT ? bf2f(((const unsigned short*)B1v)[n])
                                : ((const float*)B1v)[n];
        }
    float b2v[8];
    #pragma unroll
    for (int t = 0; t < 8; ++t)
        b2v[t] = DT ? bf2f(((const unsigned short*)B2v)[t * 16 + l16])
                    : ((const float*)B2v)[t * 16 + l16];

    float* fs = outs[wave];
    const int gw = blockIdx.x * 4 + wave, nw = gridDim.x * 4;

    // software-pipeline state: current seg's count + tiles 0,1
    unsigned c_cur = 0;
    short8 r0 = {}, r1 = {};
    if (gw < NSEG) {
        c_cur = cnt[gw];
        r0 = row_tile(Xs, gw, 0, l16, quad);
        r1 = row_tile(Xs, gw, 1, l16, quad);
    }

    for (int seg = gw; seg < NSEG; seg += nw) {
        const int c_raw = (int)c_cur;
        const int c  = min(c_raw, CAPX);
        const int nt = (c + 15) >> 4;

        // on-demand tiles 2,3 for CURRENT seg (count known one iter ahead;
        // issued before compute so they hide under tiles 0,1's MFMA)
        short8 r2 = {}, r3 = {};
        if (nt > 2) r2 = row_tile(Xs, seg, 2, l16, quad);
        if (nt > 3) r3 = row_tile(Xs, seg, 3, l16, quad);

        // prefetch NEXT seg: count + tiles 0,1 (unconditional addresses)
        const int segn = seg + nw;
        unsigned cn = 0;
        short8 r0n = {}, r1n = {};
        if (segn < NSEG) {
            cn  = cnt[segn];
            r0n = row_tile(Xs, segn, 0, l16, quad);
            r1n = row_tile(Xs, segn, 1, l16, quad);
        }

        float vmax[8];
        #pragma unroll
        for (int t = 0; t < 8; ++t) vmax[t] = 0.f;

        if (c_raw > CAPX) {
            // overflow (never on this data): full index-gather path
            const int c2 = min(c_raw, CAP);
            const int nt2 = (c2 + 15) >> 4, last = c2 - 1;
            const size_t base = (size_t)seg * CAP;
            for (int ti = 0; ti < nt2; ++ti) {
                int pid = slots[base + min(ti * 16 + l16, last)];
                pid = min(max(pid, 0), NPTS - 1);
                const short8 acur = load_x(Xv, pid, quad, DT);
                tile_mlp(acur, w1f, w2f, b1v, b2v, vmax, quad, 16, true);
            }
        } else if (c > 0) {
            #pragma unroll
            for (int ti = 0; ti < 4; ++ti) {
                if (ti < nt) {
                    const short8 acur = (ti == 0) ? r0 : (ti == 1) ? r1
                                      : (ti == 2) ? r2 : r3;
                    const int lim = c - ti * 16;
                    tile_mlp(acur, w1f, w2f, b1v, b2v, vmax, quad,
                             lim, lim >= 16);
                }
            }
        }

        // cross-quad reduce; 256B coalesced row store via LDS staging
        #pragma unroll
        for (int t = 0; t < 8; ++t) {
            vmax[t] = fmaxf(vmax[t], __shfl_xor(vmax[t], 16, 64));
            vmax[t] = fmaxf(vmax[t], __shfl_xor(vmax[t], 32, 64));
        }
        if (quad == 0) {
            #pragma unroll
            for (int t = 0; t < 8; ++t) fs[t * 16 + l16] = vmax[t];
        }
        __builtin_amdgcn_s_waitcnt(0xC07F);   // lgkmcnt(0): LDS w->r (same wave)
        const floatx2 o2 = ((const floatx2*)fs)[lane];
        if (DT) {
            ((unsigned*)outv)[seg * 64 + lane] = cvt_pk_bf16(o2[0], o2[1]);
        } else {
            ((floatx2*)outv)[seg * 64 + lane] = o2;
        }
        __builtin_amdgcn_s_waitcnt(0xC07F);   // fs reads before next seg's writes

        c_cur = cn; r0 = r0n; r1 = r1n;       // rotate pipeline
    }
}

// ==================== R6 fallback path (ws too small) ====================
__global__ __launch_bounds__(256)
void build_slots(const unsigned* __restrict__ idxw,
                 const unsigned* __restrict__ Xw,
                 unsigned* __restrict__ cnt,
                 int* __restrict__ slots,
                 unsigned* __restrict__ flags)
{
    __shared__ unsigned sc;
    const int idx64 = probe_idx64(idxw, &sc);

    if (blockIdx.x == 0) {            // publish dtype flag for the MLP kernels
        const int isbf = probe_isbf(Xw, &sc);   // probe has leading barrier
        if (threadIdx.x == 0) flags[0] = (unsigned)isbf;
    }

    const int S  = gridDim.x * 256;
    const int i0 = blockIdx.x * 256 + threadIdx.x;
    const int i1 = i0 + S, i2 = i1 + S;

    unsigned s0 = 0xFFFFFFFFu, s1 = 0xFFFFFFFFu, s2 = 0xFFFFFFFFu;
    if (i0 < NPTS) s0 = idx64 ? idxw[2 * (size_t)i0] : idxw[i0];
    if (i1 < NPTS) s1 = idx64 ? idxw[2 * (size_t)i1] : idxw[i1];
    if (i2 < NPTS) s2 = idx64 ? idxw[2 * (size_t)i2] : idxw[i2];

    unsigned p0 = 0, p1 = 0, p2 = 0;
    if (s0 < NSEG) p0 = atomicAdd(&cnt[s0], 1u);
    if (s1 < NSEG) p1 = atomicAdd(&cnt[s1], 1u);
    if (s2 < NSEG) p2 = atomicAdd(&cnt[s2], 1u);

    if (s0 < NSEG && p0 < CAP) slots[(size_t)s0 * CAP + p0] = i0;
    if (s1 < NSEG && p1 < CAP) slots[(size_t)s1 * CAP + p1] = i1;
    if (s2 < NSEG && p2 < CAP) slots[(size_t)s2 * CAP + p2] = i2;
}

template<int DT>
__global__ __launch_bounds__(256)
void seg_mlp_max(const void* __restrict__ Xv,
                 const void* __restrict__ W1v, const void* __restrict__ B1v,
                 const void* __restrict__ W2v, const void* __restrict__ B2v,
                 const unsigned* __restrict__ cnt,
                 const int* __restrict__ slots,
                 const unsigned* __restrict__ flags,
                 void* __restrict__ outv)
{
    if (flags[0] != (unsigned)DT) return;

    __shared__ __align__(16) float outs[4][128];

    const int tid = threadIdx.x, wave = tid >> 6, lane = tid & 63;
    const int quad = lane >> 4, l16 = lane & 15;

    short8 w1f[4];
    #pragma unroll
    for (int t = 0; t < 4; ++t)
        #pragma unroll
        for (int j = 0; j < 8; ++j) {
            const int e = (quad * 8 + j) * 64 + t * 16 + l16;
            w1f[t][j] = DT ? (short)((const unsigned short*)W1v)[e]
                           : (short)f2bf(((const float*)W1v)[e]);
        }
    short8 w2f[2][8];
    #pragma unroll
    for (int kt = 0; kt < 2; ++kt)
        #pragma unroll
        for (int t = 0; t < 8; ++t)
            #pragma unroll
            for (int j = 0; j < 8; ++j) {
                const int k = kt * 32 + (j >> 2) * 16 + quad * 4 + (j & 3);
                const int e = k * 128 + t * 16 + l16;
                w2f[kt][t][j] = DT ? (short)((const unsigned short*)W2v)[e]
                                   : (short)f2bf(((const float*)W2v)[e]);
            }
    float b1v[16];
    #pragma unroll
    for (int t = 0; t < 4; ++t)
        #pragma unroll
        for (int r = 0; r < 4; ++r) {
            const int n = t * 16 + quad * 4 + r;
            b1v[t * 4 + r] = DT ? bf2f(((const unsigned short*)B1v)[n])
                                : ((const float*)B1v)[n];
        }
    float b2v[8];
    #pragma unroll
    for (int t = 0; t < 8; ++t)
        b2v[t] = DT ? bf2f(((const unsigned short*)B2v)[t * 16 + l16])
                    : ((const float*)B2v)[t * 16 + l16];

    float* fs = outs[wave];
    const int gw = blockIdx.x * 4 + wave, nw = gridDim.x * 4;

    for (int seg = gw; seg < NSEG; seg += nw) {
        const int c = min((int)cnt[seg], CAP);

        float vmax[8];
        #pragma unroll
        for (int t = 0; t < 8; ++t) vmax[t] = 0.f;

        if (c > 0) {
            const int nt = (c + 15) >> 4, last = c - 1;
            const size_t base = (size_t)seg * CAP;

            short8 abuf[2];
            abuf[0] = load_x(Xv, slots[base + min(l16, last)], quad, DT);
            if (nt > 1)
                abuf[1] = load_x(Xv, slots[base + min(16 + l16, last)], quad, DT);

            for (int ti = 0; ti < nt; ++ti) {
                const short8 acur = abuf[ti & 1];
                if (ti + 2 < nt)
                    abuf[ti & 1] = load_x(
                        Xv, slots[base + min((ti + 2) * 16 + l16, last)], quad, DT);
                tile_mlp(acur, w1f, w2f, b1v, b2v, vmax, quad, 16, true);
            }
        }

        #pragma unroll
        for (int t = 0; t < 8; ++t) {
            vmax[t] = fmaxf(vmax[t], __shfl_xor(vmax[t], 16, 64));
            vmax[t] = fmaxf(vmax[t], __shfl_xor(vmax[t], 32, 64));
        }
        if (quad == 0) {
            #pragma unroll
            for (int t = 0; t < 8; ++t) fs[t * 16 + l16] = vmax[t];
        }
        __builtin_amdgcn_s_waitcnt(0xC07F);
        const floatx2 o2 = ((const floatx2*)fs)[lane];
        if (DT) {
            ((unsigned*)outv)[seg * 64 + lane] = cvt_pk_bf16(o2[0], o2[1]);
        } else {
            ((floatx2*)outv)[seg * 64 + lane] = o2;
        }
        __builtin_amdgcn_s_waitcnt(0xC07F);
    }
}

// ==================== host launch ====================
extern "C" void kernel_launch(void* const* d_in, const int* in_sizes, int n_in,
                              void* d_out, int out_size, void* d_ws, size_t ws_size,
                              hipStream_t stream)
{
    const void* X   = d_in[0];
    const void* idx = d_in[1];
    const void* W1  = d_in[2];
    const void* B1  = d_in[3];
    const void* W2  = d_in[4];
    const void* B2  = d_in[5];

    // ws layout: cnt 200,000 B | flags 64 B | slots 24 MB | Xs 204.8 MB
    char* w = (char*)d_ws;
    unsigned* cnt   = (unsigned*)w;  w += ((size_t)NSEG * 4 + 63) & ~63ull;
    unsigned* flags = (unsigned*)w;  w += 64;
    int*      slots = (int*)w;       w += (size_t)NSEG * CAP * 4;
    unsigned short* Xs = (unsigned short*)w;

    const size_t need_fast =
        (((size_t)NSEG * 4 + 63) & ~63ull) + 64 +
        (size_t)NSEG * CAP * 4 + (size_t)NSEG * CAPX * 64;

    hipMemsetAsync(cnt, 0, (size_t)NSEG * 4, stream);

    if (ws_size >= need_fast) {
        build_rows<<<3072, 256, 0, stream>>>((const unsigned*)idx, (const unsigned*)X,
                                             cnt, slots, Xs, flags);
        seg_mlp_rows<1><<<4096, 256, 0, stream>>>(X, W1, B1, W2, B2, cnt, slots,
                                                  Xs, flags, d_out);
        seg_mlp_rows<0><<<4096, 256, 0, stream>>>(X, W1, B1, W2, B2, cnt, slots,
                                                  Xs, flags, d_out);
    } else {
        build_slots<<<2048, 256, 0, stream>>>((const unsigned*)idx, (const unsigned*)X,
                                              cnt, slots, flags);
        seg_mlp_max<1><<<4096, 256, 0, stream>>>(X, W1, B1, W2, B2, cnt, slots,
                                                 flags, d_out);
        seg_mlp_max<0><<<4096, 256, 0, stream>>>(X, W1, B1, W2, B2, cnt, slots,
                                                 flags, d_out);
    }
}